// Round 13
// baseline (160.001 us; speedup 1.0000x reference)
//
#include <hip/hip_runtime.h>
#include <stdint.h>

// FilteredLReLU: up2(17-tap) -> *2 -> lrelu(0.01) -> down2(17-tap), fused.
// R9 f16-dot2 streaming base + instruction-count cuts:
//   1. tap packing hoisted to a 1-thread setup kernel -> d_ws (s_loads in main)
//   2. packed lrelu: pkrtz(ae,ao) then v_pk_mul/v_pk_max (3 ops vs 5)
//   3. nontemporal output stores (don't evict x-stream from L2)
//
//   ge[m] = lrelu( sum fe[j]*x[m-4+j] ), go[m] = lrelu( sum fo[j]*x[m-3+j] )
//   z[t]  = sum de[j]*ge[t-4+j] + sum dd[j]*go[t-4+j]   (UP gain in fe/fo)

#define T_LEN 32768
#define R_OUT 16
#define TPR   (T_LEN / R_OUT)   // 2048 threads per row

typedef __fp16 h16x2 __attribute__((ext_vector_type(2)));
typedef float  f32x4 __attribute__((ext_vector_type(4)));

__device__ __forceinline__ uint32_t pkrtz(float lo, float hi) {
    h16x2 p = __builtin_amdgcn_cvt_pkrtz(lo, hi);
    return __builtin_bit_cast(uint32_t, p);
}
__device__ __forceinline__ float fdot2(uint32_t a, uint32_t b, float c) {
    return __builtin_amdgcn_fdot2(__builtin_bit_cast(h16x2, a),
                                  __builtin_bit_cast(h16x2, b), c, false);
}
__device__ __forceinline__ float lrelu(float v) { return fmaxf(v, 0.01f * v); }

// packed leaky-relu on 2 f16 lanes: max(p, 0.01*p)
__device__ __forceinline__ uint32_t pk_lrelu(uint32_t p, uint32_t c01) {
    uint32_t m, r;
    asm("v_pk_mul_f16 %0, %1, %2" : "=v"(m) : "v"(p), "v"(c01));
    asm("v_pk_max_f16 %0, %1, %2" : "=v"(r) : "v"(p), "v"(m));
    return r;
}

// ---- setup: pack taps once into ws[0..17] ----
// ws[0..4]=fep (fe pairs, last=(fe8,0)), ws[5..8]=fop, ws[9..17]=dp
__global__ void pack_taps(const float* __restrict__ up,
                          const float* __restrict__ dn,
                          uint32_t* __restrict__ ws) {
    if (threadIdx.x == 0 && blockIdx.x == 0) {
        float fe[9], fo[8], de[9], dd[8];
        #pragma unroll
        for (int j = 0; j < 9; ++j) { fe[j] = 2.0f * up[2*j]; de[j] = dn[2*j]; }
        #pragma unroll
        for (int j = 0; j < 8; ++j) { fo[j] = 2.0f * up[2*j+1]; dd[j] = dn[2*j+1]; }
        #pragma unroll
        for (int q = 0; q < 4; ++q) ws[q] = pkrtz(fe[2*q], fe[2*q+1]);
        ws[4] = pkrtz(fe[8], 0.0f);
        #pragma unroll
        for (int q = 0; q < 4; ++q) ws[5+q] = pkrtz(fo[2*q], fo[2*q+1]);
        #pragma unroll
        for (int j = 0; j < 8; ++j) ws[9+j] = pkrtz(de[j], dd[j]);
        ws[17] = pkrtz(de[8], 0.0f);
    }
}

__global__ __launch_bounds__(256, 2) void flrelu_dot2c(
    const float* __restrict__ x,
    const float* __restrict__ up,
    const float* __restrict__ dn,
    const uint32_t* __restrict__ tw,
    float* __restrict__ out)
{
    const int gid = blockIdx.x * 256 + threadIdx.x;
    const int row = gid >> 11;                 // / TPR
    const int t   = (gid & (TPR - 1)) * R_OUT;
    const float* __restrict__ xrow = x + (size_t)row * T_LEN;
    float* __restrict__ orow       = out + (size_t)row * T_LEN;

    if (t >= 8 && t + R_OUT + 8 <= T_LEN) {
        // -------- fast f16-dot2 path (interior) --------
        // taps: uniform pointer + constant idx -> s_load (SGPRs)
        uint32_t fep[5], fop[4], dp[9];
        #pragma unroll
        for (int q = 0; q < 5; ++q) fep[q] = tw[q];
        #pragma unroll
        for (int q = 0; q < 4; ++q) fop[q] = tw[5 + q];
        #pragma unroll
        for (int j = 0; j < 9; ++j) dp[j] = tw[9 + j];
        const uint32_t c01 = pkrtz(0.01f, 0.01f);

        // load x[t-8 .. t+23]
        float xv[32];
        const float4* xp = reinterpret_cast<const float4*>(xrow + t - 8);
        #pragma unroll
        for (int k = 0; k < 8; ++k) {
            float4 v = xp[k];
            xv[4*k+0] = v.x; xv[4*k+1] = v.y;
            xv[4*k+2] = v.z; xv[4*k+3] = v.w;
        }

        // f16 pairs: aligned + shifted-by-1
        uint32_t xa[16], xs[16];
        #pragma unroll
        for (int k = 0; k < 16; ++k) xa[k] = pkrtz(xv[2*k], xv[2*k+1]);
        #pragma unroll
        for (int k = 0; k < 15; ++k)
            xs[k] = (xa[k] >> 16) | (xa[k+1] << 16);     // v_alignbit_b32
        xs[15] = xa[15] >> 16;

        float acc[R_OUT];

        #pragma unroll
        for (int ml = 0; ml < R_OUT + 8; ++ml) {
            const int e = ml / 2;
            float ae;
            if ((ml & 1) == 0) {
                ae = fdot2(fep[0], xa[e], 0.0f);
                ae = fdot2(fep[1], xa[e+1], ae);
                ae = fdot2(fep[2], xa[e+2], ae);
                ae = fdot2(fep[3], xa[e+3], ae);
                ae = fdot2(fep[4], xa[e+4], ae);
            } else {
                ae = fdot2(fep[0], xs[e], 0.0f);
                ae = fdot2(fep[1], xs[e+1], ae);
                ae = fdot2(fep[2], xs[e+2], ae);
                ae = fdot2(fep[3], xs[e+3], ae);
                ae = fdot2(fep[4], xs[e+4], ae);
            }

            float ao = 0.0f;
            if (ml < R_OUT + 7) {
                if ((ml & 1) == 0) {
                    ao = fdot2(fop[0], xs[e], 0.0f);
                    ao = fdot2(fop[1], xs[e+1], ao);
                    ao = fdot2(fop[2], xs[e+2], ao);
                    ao = fdot2(fop[3], xs[e+3], ao);
                } else {
                    ao = fdot2(fop[0], xa[e+1], 0.0f);
                    ao = fdot2(fop[1], xa[e+2], ao);
                    ao = fdot2(fop[2], xa[e+3], ao);
                    ao = fdot2(fop[3], xa[e+4], ao);
                }
            }

            // packed lrelu on (ae, ao) -> p = (ge, go) in f16
            const uint32_t p = pk_lrelu(pkrtz(ae, ao), c01);

            // scatter: acc[r] += de[ml-r]*ge + dd[ml-r]*go
            #pragma unroll
            for (int r = 0; r < R_OUT; ++r) {
                if (r >= ml - 8 && r <= ml) {
                    if (r == ml) acc[r] = fdot2(dp[0], p, 0.0f);
                    else         acc[r] = fdot2(dp[ml-r], p, acc[r]);
                }
            }
        }

        f32x4* op = reinterpret_cast<f32x4*>(orow + t);
        #pragma unroll
        for (int k = 0; k < R_OUT / 4; ++k) {
            f32x4 v = {acc[4*k+0], acc[4*k+1], acc[4*k+2], acc[4*k+3]};
            __builtin_nontemporal_store(v, op + k);
        }
    } else {
        // -------- scalar f32 boundary path --------
        float fe[9], fo[8], de[9], dd[8];
        #pragma unroll
        for (int j = 0; j < 9; ++j) { fe[j] = 2.0f * up[2*j]; de[j] = dn[2*j]; }
        #pragma unroll
        for (int j = 0; j < 8; ++j) { fo[j] = 2.0f * up[2*j+1]; dd[j] = dn[2*j+1]; }

        float xv[R_OUT + 16];
        #pragma unroll
        for (int i = 0; i < R_OUT + 16; ++i) {
            int g = t - 8 + i;
            xv[i] = (g >= 0 && g < T_LEN) ? xrow[g] : 0.0f;
        }
        float acc[R_OUT];
        #pragma unroll
        for (int r = 0; r < R_OUT; ++r) acc[r] = 0.0f;

        #pragma unroll
        for (int ml = 0; ml < R_OUT + 8; ++ml) {
            float ae = 0.0f;
            #pragma unroll
            for (int j = 0; j < 9; ++j) ae = fmaf(fe[j], xv[ml+j], ae);
            float g = lrelu(ae);
            int m = t - 4 + ml;
            if (m < 0 || m >= T_LEN) g = 0.0f;   // dn conv zero-pads y
            #pragma unroll
            for (int r = 0; r < R_OUT; ++r)
                if (r >= ml - 8 && r <= ml)
                    acc[r] = fmaf(de[ml-r], g, acc[r]);

            if (ml < R_OUT + 7) {
                float ao = 0.0f;
                #pragma unroll
                for (int j = 0; j < 8; ++j) ao = fmaf(fo[j], xv[ml+1+j], ao);
                float h = lrelu(ao);
                if (m < 0 || m >= T_LEN) h = 0.0f;
                #pragma unroll
                for (int r = 0; r < R_OUT; ++r)
                    if (r >= ml - 7 && r <= ml)
                        acc[r] = fmaf(dd[ml-r], h, acc[r]);
            }
        }

        float4* op = reinterpret_cast<float4*>(orow + t);
        #pragma unroll
        for (int k = 0; k < R_OUT / 4; ++k)
            op[k] = make_float4(acc[4*k+0], acc[4*k+1], acc[4*k+2], acc[4*k+3]);
    }
}

extern "C" void kernel_launch(void* const* d_in, const int* in_sizes, int n_in,
                              void* d_out, int out_size, void* d_ws, size_t ws_size,
                              hipStream_t stream) {
    const float* x  = (const float*)d_in[0];
    const float* up = (const float*)d_in[1];
    const float* dn = (const float*)d_in[2];
    float* out      = (float*)d_out;
    uint32_t* ws    = (uint32_t*)d_ws;

    pack_taps<<<1, 64, 0, stream>>>(up, dn, ws);

    const int rows    = in_sizes[0] / T_LEN;         // 2048
    const int threads = rows * TPR;                  // 4.19M
    flrelu_dot2c<<<threads / 256, 256, 0, stream>>>(x, up, dn, ws, out);
}

// Round 14
// 135.725 us; speedup vs baseline: 1.1789x; 1.1789x over previous
//
#include <hip/hip_runtime.h>
#include <stdint.h>

// FilteredLReLU: up2(17-tap) -> *2 -> lrelu(0.01) -> down2(17-tap), fused.
// Full v_pk_fma_f16 SWAR version (R9 structure, dot2 -> pk_fma):
//   - intermediates computed as packed pairs (ge[2q],ge[2q+1]) etc.
//   - packed lrelu (pk_mul + pk_max)
//   - scatter into packed f16 output-pair accumulators
//   pk_fma_f16 is full-rate (2 f16 MACs / 2cyc issue = 2x f32 FLOP rate);
//   v_dot2 measured ~half that (R6 vs R9: -35% ops, only -8% time).
//
//   ge[m] = lrelu( sum fe[j]*x[m-4+j] ), go[m] = lrelu( sum fo[j]*x[m-3+j] )
//   z[t]  = sum de[j]*ge[t-4+j] + sum dd[j]*go[t-4+j]   (UP gain in fe/fo)

#define T_LEN 32768
#define R_OUT 16
#define TPR   (T_LEN / R_OUT)   // 2048 threads per row

typedef __fp16   cvt2 __attribute__((ext_vector_type(2)));  // pkrtz result
typedef _Float16 hpair __attribute__((ext_vector_type(2))); // arithmetic

__device__ __forceinline__ uint32_t pkrtz(float lo, float hi) {
    cvt2 p = __builtin_amdgcn_cvt_pkrtz(lo, hi);
    return __builtin_bit_cast(uint32_t, p);
}
__device__ __forceinline__ hpair h2(uint32_t u) {
    return __builtin_bit_cast(hpair, u);
}
__device__ __forceinline__ uint32_t u32(hpair h) {
    return __builtin_bit_cast(uint32_t, h);
}
__device__ __forceinline__ hpair pk_fma(hpair a, hpair b, hpair c) {
    return __builtin_elementwise_fma(a, b, c);
}
__device__ __forceinline__ hpair pk_lrelu(hpair v, hpair c01) {
    return __builtin_elementwise_max(v, v * c01);
}
__device__ __forceinline__ float lrelu(float v) { return fmaxf(v, 0.01f * v); }
__device__ __forceinline__ uint32_t rfl(uint32_t v) {
    return __builtin_amdgcn_readfirstlane(v);
}

__global__ __launch_bounds__(256, 2) void flrelu_pk(
    const float* __restrict__ x,
    const float* __restrict__ up,
    const float* __restrict__ dn,
    float* __restrict__ out)
{
    const int gid = blockIdx.x * 256 + threadIdx.x;
    const int row = gid >> 11;                 // / TPR
    const int t   = (gid & (TPR - 1)) * R_OUT;
    const float* __restrict__ xrow = x + (size_t)row * T_LEN;
    float* __restrict__ orow       = out + (size_t)row * T_LEN;

    // f32 taps (uniform). UP gain folded into fe/fo.
    float fe[9], fo[8], de[9], dd[8];
    #pragma unroll
    for (int j = 0; j < 9; ++j) { fe[j] = 2.0f * up[2*j]; de[j] = dn[2*j]; }
    #pragma unroll
    for (int j = 0; j < 8; ++j) { fo[j] = 2.0f * up[2*j+1]; dd[j] = dn[2*j+1]; }

    if (t >= 8 && t + R_OUT + 8 <= T_LEN) {
        // -------- interior: packed f16 SWAR path --------
        // broadcast tap pairs -> SGPRs
        hpair feB[9], foB[8], deB[9], ddB[8];
        #pragma unroll
        for (int j = 0; j < 9; ++j) {
            feB[j] = h2(rfl(pkrtz(fe[j], fe[j])));
            deB[j] = h2(rfl(pkrtz(de[j], de[j])));
        }
        #pragma unroll
        for (int j = 0; j < 8; ++j) {
            foB[j] = h2(rfl(pkrtz(fo[j], fo[j])));
            ddB[j] = h2(rfl(pkrtz(dd[j], dd[j])));
        }
        const hpair c01 = h2(pkrtz(0.01f, 0.01f));

        // load x[t-8 .. t+23]
        float xv[32];
        const float4* xp = reinterpret_cast<const float4*>(xrow + t - 8);
        #pragma unroll
        for (int k = 0; k < 8; ++k) {
            float4 v = xp[k];
            xv[4*k+0] = v.x; xv[4*k+1] = v.y;
            xv[4*k+2] = v.z; xv[4*k+3] = v.w;
        }

        // f16 pairs: aligned xa[k]=(xv[2k],xv[2k+1]); shifted xs[k]=(xv[2k+1],xv[2k+2])
        uint32_t xau[16], xsu[15];
        #pragma unroll
        for (int k = 0; k < 16; ++k) xau[k] = pkrtz(xv[2*k], xv[2*k+1]);
        #pragma unroll
        for (int k = 0; k < 15; ++k)
            xsu[k] = (xau[k] >> 16) | (xau[k+1] << 16);   // v_alignbit_b32

        // intermediate pairs ga[q]=(ge[2q],ge[2q+1]), goa[q]=(go[2q],go[2q+1])
        hpair ga[12], goa[12];
        #pragma unroll
        for (int q = 0; q < 12; ++q) {
            // even: sum_{a=0..4} fe[2a]*xa[q+a] + sum_{a=0..3} fe[2a+1]*xs[q+a]
            hpair s = feB[0] * h2(xau[q]);
            #pragma unroll
            for (int a = 1; a < 5; ++a) s = pk_fma(feB[2*a], h2(xau[q+a]), s);
            #pragma unroll
            for (int a = 0; a < 4; ++a) s = pk_fma(feB[2*a+1], h2(xsu[q+a]), s);
            ga[q] = pk_lrelu(s, c01);

            // odd: sum_{a=0..3} fo[2a]*xs[q+a] + sum_{a=0..3} fo[2a+1]*xa[q+a+1]
            hpair r = foB[0] * h2(xsu[q]);
            #pragma unroll
            for (int a = 1; a < 4; ++a) r = pk_fma(foB[2*a], h2(xsu[q+a]), r);
            #pragma unroll
            for (int a = 0; a < 4; ++a) r = pk_fma(foB[2*a+1], h2(xau[q+a+1]), r);
            goa[q] = pk_lrelu(r, c01);
        }

        // shifted pairs gs[q]=(ge[2q+1],ge[2q+2]), gos[q]=(go[2q+1],go[2q+2])
        hpair gs[11], gos[11];
        #pragma unroll
        for (int q = 0; q < 11; ++q) {
            gs[q]  = h2((u32(ga[q])  >> 16) | (u32(ga[q+1])  << 16));
            gos[q] = h2((u32(goa[q]) >> 16) | (u32(goa[q+1]) << 16));
        }

        // scatter: zp[p] = (z[2p], z[2p+1])
        //   = sum_{a=0..4} de[2a]*ga[p+a] + sum_{a=0..3} de[2a+1]*gs[p+a]
        //   + sum_{a=0..3} dd[2a]*goa[p+a] + sum_{a=0..3} dd[2a+1]*gos[p+a]
        hpair zp[8];
        #pragma unroll
        for (int p = 0; p < 8; ++p) {
            hpair s = deB[0] * ga[p];
            #pragma unroll
            for (int a = 1; a < 5; ++a) s = pk_fma(deB[2*a], ga[p+a], s);
            #pragma unroll
            for (int a = 0; a < 4; ++a) s = pk_fma(deB[2*a+1], gs[p+a], s);
            #pragma unroll
            for (int a = 0; a < 4; ++a) s = pk_fma(ddB[2*a], goa[p+a], s);
            #pragma unroll
            for (int a = 0; a < 4; ++a) s = pk_fma(ddB[2*a+1], gos[p+a], s);
            zp[p] = s;
        }

        float4* op = reinterpret_cast<float4*>(orow + t);
        #pragma unroll
        for (int k = 0; k < 4; ++k)
            op[k] = make_float4((float)zp[2*k][0], (float)zp[2*k][1],
                                (float)zp[2*k+1][0], (float)zp[2*k+1][1]);
    } else {
        // -------- scalar f32 boundary path --------
        float xv[R_OUT + 16];
        #pragma unroll
        for (int i = 0; i < R_OUT + 16; ++i) {
            int g = t - 8 + i;
            xv[i] = (g >= 0 && g < T_LEN) ? xrow[g] : 0.0f;
        }
        float acc[R_OUT];
        #pragma unroll
        for (int r = 0; r < R_OUT; ++r) acc[r] = 0.0f;

        #pragma unroll
        for (int ml = 0; ml < R_OUT + 8; ++ml) {
            float ae = 0.0f;
            #pragma unroll
            for (int j = 0; j < 9; ++j) ae = fmaf(fe[j], xv[ml+j], ae);
            float g = lrelu(ae);
            int m = t - 4 + ml;
            if (m < 0 || m >= T_LEN) g = 0.0f;   // dn conv zero-pads y
            #pragma unroll
            for (int r = 0; r < R_OUT; ++r)
                if (r >= ml - 8 && r <= ml)
                    acc[r] = fmaf(de[ml-r], g, acc[r]);

            if (ml < R_OUT + 7) {
                float ao = 0.0f;
                #pragma unroll
                for (int j = 0; j < 8; ++j) ao = fmaf(fo[j], xv[ml+1+j], ao);
                float h = lrelu(ao);
                if (m < 0 || m >= T_LEN) h = 0.0f;
                #pragma unroll
                for (int r = 0; r < R_OUT; ++r)
                    if (r >= ml - 7 && r <= ml)
                        acc[r] = fmaf(dd[ml-r], h, acc[r]);
            }
        }

        float4* op = reinterpret_cast<float4*>(orow + t);
        #pragma unroll
        for (int k = 0; k < R_OUT / 4; ++k)
            op[k] = make_float4(acc[4*k+0], acc[4*k+1], acc[4*k+2], acc[4*k+3]);
    }
}

extern "C" void kernel_launch(void* const* d_in, const int* in_sizes, int n_in,
                              void* d_out, int out_size, void* d_ws, size_t ws_size,
                              hipStream_t stream) {
    const float* x  = (const float*)d_in[0];
    const float* up = (const float*)d_in[1];
    const float* dn = (const float*)d_in[2];
    float* out      = (float*)d_out;

    const int rows    = in_sizes[0] / T_LEN;         // 2048
    const int threads = rows * TPR;                  // 4.19M
    flrelu_pk<<<threads / 256, 256, 0, stream>>>(x, up, dn, out);
}

// Round 15
// 119.572 us; speedup vs baseline: 1.3381x; 1.1351x over previous
//
#include <hip/hip_runtime.h>
#include <stdint.h>

// FilteredLReLU: up2(17-tap) -> *2 -> lrelu(0.01) -> down2(17-tap), fused.
// v_pk_fma_f16 SWAR (R14) with R_OUT=8: halved per-thread latency chain,
// 2x wave count, no launch_bounds -> test the latency/overlap hypothesis.
//
//   ge[m] = lrelu( sum fe[j]*x[m-4+j] ), go[m] = lrelu( sum fo[j]*x[m-3+j] )
//   z[t]  = sum de[j]*ge[t-4+j] + sum dd[j]*go[t-4+j]   (UP gain in fe/fo)

#define T_LEN 32768
#define R_OUT 8
#define TPR   (T_LEN / R_OUT)   // 4096 threads per row

typedef __fp16   cvt2 __attribute__((ext_vector_type(2)));  // pkrtz result
typedef _Float16 hpair __attribute__((ext_vector_type(2))); // arithmetic

__device__ __forceinline__ uint32_t pkrtz(float lo, float hi) {
    cvt2 p = __builtin_amdgcn_cvt_pkrtz(lo, hi);
    return __builtin_bit_cast(uint32_t, p);
}
__device__ __forceinline__ hpair h2(uint32_t u) {
    return __builtin_bit_cast(hpair, u);
}
__device__ __forceinline__ uint32_t u32(hpair h) {
    return __builtin_bit_cast(uint32_t, h);
}
__device__ __forceinline__ hpair pk_fma(hpair a, hpair b, hpair c) {
    return __builtin_elementwise_fma(a, b, c);
}
__device__ __forceinline__ hpair pk_lrelu(hpair v, hpair c01) {
    return __builtin_elementwise_max(v, v * c01);
}
__device__ __forceinline__ float lrelu(float v) { return fmaxf(v, 0.01f * v); }
__device__ __forceinline__ uint32_t rfl(uint32_t v) {
    return __builtin_amdgcn_readfirstlane(v);
}

__global__ void flrelu_pk8(
    const float* __restrict__ x,
    const float* __restrict__ up,
    const float* __restrict__ dn,
    float* __restrict__ out)
{
    const int gid = blockIdx.x * 256 + threadIdx.x;
    const int row = gid >> 12;                 // / TPR
    const int t   = (gid & (TPR - 1)) * R_OUT;
    const float* __restrict__ xrow = x + (size_t)row * T_LEN;
    float* __restrict__ orow       = out + (size_t)row * T_LEN;

    // f32 taps (uniform). UP gain folded into fe/fo.
    float fe[9], fo[8], de[9], dd[8];
    #pragma unroll
    for (int j = 0; j < 9; ++j) { fe[j] = 2.0f * up[2*j]; de[j] = dn[2*j]; }
    #pragma unroll
    for (int j = 0; j < 8; ++j) { fo[j] = 2.0f * up[2*j+1]; dd[j] = dn[2*j+1]; }

    if (t >= 8 && t + R_OUT + 8 <= T_LEN) {
        // -------- interior: packed f16 SWAR path --------
        hpair feB[9], foB[8], deB[9], ddB[8];
        #pragma unroll
        for (int j = 0; j < 9; ++j) {
            feB[j] = h2(rfl(pkrtz(fe[j], fe[j])));
            deB[j] = h2(rfl(pkrtz(de[j], de[j])));
        }
        #pragma unroll
        for (int j = 0; j < 8; ++j) {
            foB[j] = h2(rfl(pkrtz(fo[j], fo[j])));
            ddB[j] = h2(rfl(pkrtz(dd[j], dd[j])));
        }
        const hpair c01 = h2(pkrtz(0.01f, 0.01f));

        // load x[t-8 .. t+15]  (6 aligned float4)
        float xv[24];
        const float4* xp = reinterpret_cast<const float4*>(xrow + t - 8);
        #pragma unroll
        for (int k = 0; k < 6; ++k) {
            float4 v = xp[k];
            xv[4*k+0] = v.x; xv[4*k+1] = v.y;
            xv[4*k+2] = v.z; xv[4*k+3] = v.w;
        }

        // f16 pairs: aligned xa[k]=(xv[2k],xv[2k+1]); shifted xs[k]=(xv[2k+1],xv[2k+2])
        uint32_t xau[12], xsu[11];
        #pragma unroll
        for (int k = 0; k < 12; ++k) xau[k] = pkrtz(xv[2*k], xv[2*k+1]);
        #pragma unroll
        for (int k = 0; k < 11; ++k)
            xsu[k] = (xau[k] >> 16) | (xau[k+1] << 16);   // v_alignbit_b32

        // intermediate pairs ga[q]=(ge[t-4+2q], ge[t-4+2q+1]), q=0..7; same for go
        hpair ga[8], goa[8];
        #pragma unroll
        for (int q = 0; q < 8; ++q) {
            hpair s = feB[0] * h2(xau[q]);
            #pragma unroll
            for (int a = 1; a < 5; ++a) s = pk_fma(feB[2*a], h2(xau[q+a]), s);
            #pragma unroll
            for (int a = 0; a < 4; ++a) s = pk_fma(feB[2*a+1], h2(xsu[q+a]), s);
            ga[q] = pk_lrelu(s, c01);

            hpair r = foB[0] * h2(xsu[q]);
            #pragma unroll
            for (int a = 1; a < 4; ++a) r = pk_fma(foB[2*a], h2(xsu[q+a]), r);
            #pragma unroll
            for (int a = 0; a < 4; ++a) r = pk_fma(foB[2*a+1], h2(xau[q+a+1]), r);
            goa[q] = pk_lrelu(r, c01);
        }

        // shifted pairs
        hpair gs[7], gos[7];
        #pragma unroll
        for (int q = 0; q < 7; ++q) {
            gs[q]  = h2((u32(ga[q])  >> 16) | (u32(ga[q+1])  << 16));
            gos[q] = h2((u32(goa[q]) >> 16) | (u32(goa[q+1]) << 16));
        }

        // scatter: zp[p] = (z[t+2p], z[t+2p+1]), p=0..3
        hpair zp[4];
        #pragma unroll
        for (int p = 0; p < 4; ++p) {
            hpair s = deB[0] * ga[p];
            #pragma unroll
            for (int a = 1; a < 5; ++a) s = pk_fma(deB[2*a], ga[p+a], s);
            #pragma unroll
            for (int a = 0; a < 4; ++a) s = pk_fma(deB[2*a+1], gs[p+a], s);
            #pragma unroll
            for (int a = 0; a < 4; ++a) s = pk_fma(ddB[2*a], goa[p+a], s);
            #pragma unroll
            for (int a = 0; a < 4; ++a) s = pk_fma(ddB[2*a+1], gos[p+a], s);
            zp[p] = s;
        }

        float4* op = reinterpret_cast<float4*>(orow + t);
        #pragma unroll
        for (int k = 0; k < 2; ++k)
            op[k] = make_float4((float)zp[2*k][0], (float)zp[2*k][1],
                                (float)zp[2*k+1][0], (float)zp[2*k+1][1]);
    } else {
        // -------- scalar f32 boundary path --------
        float xv[R_OUT + 16];
        #pragma unroll
        for (int i = 0; i < R_OUT + 16; ++i) {
            int g = t - 8 + i;
            xv[i] = (g >= 0 && g < T_LEN) ? xrow[g] : 0.0f;
        }
        float acc[R_OUT];
        #pragma unroll
        for (int r = 0; r < R_OUT; ++r) acc[r] = 0.0f;

        #pragma unroll
        for (int ml = 0; ml < R_OUT + 8; ++ml) {
            float ae = 0.0f;
            #pragma unroll
            for (int j = 0; j < 9; ++j) ae = fmaf(fe[j], xv[ml+j], ae);
            float g = lrelu(ae);
            int m = t - 4 + ml;
            if (m < 0 || m >= T_LEN) g = 0.0f;   // dn conv zero-pads y
            #pragma unroll
            for (int r = 0; r < R_OUT; ++r)
                if (r >= ml - 8 && r <= ml)
                    acc[r] = fmaf(de[ml-r], g, acc[r]);

            if (ml < R_OUT + 7) {
                float ao = 0.0f;
                #pragma unroll
                for (int j = 0; j < 8; ++j) ao = fmaf(fo[j], xv[ml+1+j], ao);
                float h = lrelu(ao);
                if (m < 0 || m >= T_LEN) h = 0.0f;
                #pragma unroll
                for (int r = 0; r < R_OUT; ++r)
                    if (r >= ml - 7 && r <= ml)
                        acc[r] = fmaf(dd[ml-r], h, acc[r]);
            }
        }

        float4* op = reinterpret_cast<float4*>(orow + t);
        #pragma unroll
        for (int k = 0; k < R_OUT / 4; ++k)
            op[k] = make_float4(acc[4*k+0], acc[4*k+1], acc[4*k+2], acc[4*k+3]);
    }
}

extern "C" void kernel_launch(void* const* d_in, const int* in_sizes, int n_in,
                              void* d_out, int out_size, void* d_ws, size_t ws_size,
                              hipStream_t stream) {
    const float* x  = (const float*)d_in[0];
    const float* up = (const float*)d_in[1];
    const float* dn = (const float*)d_in[2];
    float* out      = (float*)d_out;

    const int rows    = in_sizes[0] / T_LEN;         // 2048
    const int threads = rows * TPR;                  // 8.39M
    flrelu_pk8<<<threads / 256, 256, 0, stream>>>(x, up, dn, out);
}